// Round 3
// baseline (491.842 us; speedup 1.0000x reference)
//
#include <hip/hip_runtime.h>
#include <stdint.h>

#define NB 4
#define NT 2048
#define ND 1024
#define NH 16
#define NDK 64
#define NTD 3072   // 3*ND

typedef __attribute__((ext_vector_type(8))) short short8;
typedef __attribute__((ext_vector_type(4))) float f32x4;
typedef unsigned short u16;
typedef unsigned int u32;

__device__ __forceinline__ u16 f2bf(float f) {
    u32 u = __builtin_bit_cast(u32, f);
    u += 0x7fffu + ((u >> 16) & 1u);   // RNE
    return (u16)(u >> 16);
}
__device__ __forceinline__ float bf2f(u16 s) {
    u32 u = ((u32)s) << 16;
    return __builtin_bit_cast(float, u);
}

__device__ __forceinline__ void gl_lds16(const u16* g, u16* l) {
    __builtin_amdgcn_global_load_lds(
        (const __attribute__((address_space(1))) u32*)g,
        (__attribute__((address_space(3))) u32*)l, 16, 0, 0);
}

// XOR-swizzled tile index for P: rows of 32 u16 (64B), 4 atoms of 8 u16.
__device__ __forceinline__ int swz(int row, int col) {
    return row * 32 + ((((col >> 3) ^ (row >> 1) ^ (row >> 3)) & 3) << 3) + (col & 7);
}

// ---------------- fp32 -> bf16 (RNE) ----------------
__global__ __launch_bounds__(256) void cvt_bf16(const float* __restrict__ in,
                                                u16* __restrict__ out, int n) {
    int i = (blockIdx.x * 256 + threadIdx.x) * 8;
    if (i + 8 > n) return;
    float4 a = *(const float4*)(in + i);
    float4 b = *(const float4*)(in + i + 4);
    short8 r;
    r[0] = (short)f2bf(a.x); r[1] = (short)f2bf(a.y);
    r[2] = (short)f2bf(a.z); r[3] = (short)f2bf(a.w);
    r[4] = (short)f2bf(b.x); r[5] = (short)f2bf(b.y);
    r[6] = (short)f2bf(b.z); r[7] = (short)f2bf(b.w);
    *(short8*)(out + i) = r;
}

// ---------------- bf16 GEMM: C[M,N] = A[M,K] * Bm[N,K]^T ----------------
template <typename OutT>
__global__ __launch_bounds__(256) void gemm_bt(const u16* __restrict__ A,
                                               const u16* __restrict__ Bm,
                                               OutT* __restrict__ C,
                                               int M, int N, int K) {
    __shared__ __align__(16) u16 As[128 * 32];
    __shared__ __align__(16) u16 Bs[128 * 32];
    const int tid  = threadIdx.x;
    const int wave = tid >> 6, lane = tid & 63;
    const int quad = lane >> 4, l16 = lane & 15;
    const int wm = wave >> 1, wn = wave & 1;
    const int row0 = blockIdx.x * 128, col0 = blockIdx.y * 128;

    f32x4 acc[4][4];
#pragma unroll
    for (int i = 0; i < 4; ++i)
#pragma unroll
        for (int j = 0; j < 4; ++j) acc[i][j] = (f32x4){0.f, 0.f, 0.f, 0.f};

    const u16* Ag = A + (size_t)(row0 + (tid >> 2)) * K + ((tid & 3) * 8);
    const u16* Bg = Bm + (size_t)(col0 + (tid >> 2)) * K + ((tid & 3) * 8);
    const size_t stride64 = (size_t)64 * K;
    u16* As0 = As + wave * 512;
    u16* As1 = As + 2048 + wave * 512;
    u16* Bs0 = Bs + wave * 512;
    u16* Bs1 = Bs + 2048 + wave * 512;

    for (int k0 = 0; k0 < K; k0 += 32) {
        gl_lds16(Ag + k0, As0);
        gl_lds16(Ag + k0 + stride64, As1);
        gl_lds16(Bg + k0, Bs0);
        gl_lds16(Bg + k0 + stride64, Bs1);
        __syncthreads();
        short8 af[4], bfr[4];
#pragma unroll
        for (int mi = 0; mi < 4; ++mi)
            af[mi] = *(const short8*)&As[(wm * 64 + mi * 16 + l16) * 32 + quad * 8];
#pragma unroll
        for (int ni = 0; ni < 4; ++ni)
            bfr[ni] = *(const short8*)&Bs[(wn * 64 + ni * 16 + l16) * 32 + quad * 8];
#pragma unroll
        for (int mi = 0; mi < 4; ++mi)
#pragma unroll
            for (int ni = 0; ni < 4; ++ni)
                acc[mi][ni] = __builtin_amdgcn_mfma_f32_16x16x32_bf16(
                    af[mi], bfr[ni], acc[mi][ni], 0, 0, 0);
        __syncthreads();
    }

#pragma unroll
    for (int mi = 0; mi < 4; ++mi) {
#pragma unroll
        for (int ni = 0; ni < 4; ++ni) {
            const int r = row0 + wm * 64 + mi * 16 + quad * 4;
            const int c = col0 + wn * 64 + ni * 16 + l16;
#pragma unroll
            for (int rr = 0; rr < 4; ++rr) {
                float v = acc[mi][ni][rr];
                if constexpr (sizeof(OutT) == 2)
                    C[(size_t)(r + rr) * N + c] = (OutT)f2bf(v);
                else
                    C[(size_t)(r + rr) * N + c] = (OutT)v;
            }
        }
    }
}

// ---------------- V transpose: qkv V-section -> Vt[bh][d][t] ----------------
// grid (64 bh, 32 tblk), 256 thr. LDS 64t x 64d tile, swizzled.
__global__ __launch_bounds__(256) void transpose_v(const u16* __restrict__ qkv,
                                                   u16* __restrict__ vt) {
    __shared__ __align__(16) u16 L[64 * 72];  // [t][d], row stride 72 u16
    const int tid = threadIdx.x;
    const int bh = blockIdx.x, b = bh >> 4, h = bh & 15;
    const int t0 = blockIdx.y * 64;
    const u16* Vg = qkv + ((size_t)(b * NT + t0)) * NTD + 2 * ND + h * NDK;

    const int trow = tid >> 3, g = tid & 7;
#pragma unroll
    for (int rep = 0; rep < 2; ++rep) {
        const int t = trow + rep * 32;
        short8 v = *(const short8*)(Vg + (size_t)t * NTD + g * 8);
        // swizzled atom: atom = g ^ (t & 7)
        *(short8*)&L[t * 72 + ((g ^ (t & 7)) << 3)] = v;
    }
    __syncthreads();
    const int d = tid & 63, w = tid >> 6;
    u16* O = vt + ((size_t)bh * 64 + d) * NT + t0;
#pragma unroll
    for (int rep = 0; rep < 2; ++rep) {
        const int c = w + rep * 4;
        short8 o;
#pragma unroll
        for (int j = 0; j < 8; ++j) {
            const int t = c * 8 + j;
            o[j] = L[t * 72 + ((((d >> 3) ^ (t & 7)) << 3)) + (d & 7)];
        }
        *(short8*)(O + c * 8) = o;
    }
}

// ---------------- flash prefix-LM attention (v3) ----------------
// grid (64 bh, 32 q-tiles). Barrier-free: V frags direct from global Vt,
// P round-trip through per-wave swizzled LDS. Constant-max softmax in exp2
// domain, -C folded into the QK accumulator init.
__global__ __launch_bounds__(256) void flash_prefix(const u16* __restrict__ qkv,
                                                    const u16* __restrict__ vt,
                                                    const int* __restrict__ plen,
                                                    u16* __restrict__ attn) {
    __shared__ __align__(16) u16 Pl[4 * 512];  // per-wave 16x32 swizzled

    const int tid  = threadIdx.x;
    const int wave = tid >> 6, lane = tid & 63;
    const int quad = lane >> 4, l16 = lane & 15;
    const int bh = blockIdx.x, b = bh >> 4, h = bh & 15;
    const int q0 = blockIdx.y * 64;

    int P;
    {
        bool is64 = (plen[1] == 0) && (plen[3] == 0);
        P = is64 ? plen[2 * b] : plen[b];
        P = P < 0 ? 0 : (P > NT ? NT : P);
    }

    const u16* Qg = qkv + (size_t)b * NT * NTD + h * NDK;
    const u16* Kg = Qg + ND;
    const u16* Vtb = vt + (size_t)bh * 64 * NT;   // [d][t]

    const int qbase = q0 + wave * 16;
    u16* Pw = Pl + wave * 512;

    const float C = 23.0831207f;           // 16*log2(e); cancels in o/l
    const float QSCALE = 0.18033688f;      // log2(e)/8

    // Q fragments pre-scaled into exp2 domain
    short8 qa[2];
#pragma unroll
    for (int kd = 0; kd < 2; ++kd) {
        short8 tq = *(const short8*)(Qg + (size_t)(qbase + l16) * NTD + kd * 32 + quad * 8);
#pragma unroll
        for (int j = 0; j < 8; ++j)
            tq[j] = (short)f2bf(bf2f((u16)tq[j]) * QSCALE);
        qa[kd] = tq;
    }

    f32x4 o[4];
#pragma unroll
    for (int nt = 0; nt < 4; ++nt) o[nt] = (f32x4){0.f, 0.f, 0.f, 0.f};
    float lp[4] = {0.f, 0.f, 0.f, 0.f};

    int kl[4];
#pragma unroll
    for (int rr = 0; rr < 4; ++rr) {
        const int qrow = qbase + quad * 4 + rr;
        kl[rr] = (qrow < P) ? P : (qrow + 1);
    }
    const int klmin = (qbase < P) ? P : (qbase + 1);  // wave-uniform
    const int kmax = (q0 + 64 > P) ? (q0 + 64) : P;   // block-uniform

    for (int k0 = 0; k0 < kmax; k0 += 32) {
        // S = Q K^T + (-C)  (exp2-domain, pre-scaled)
        f32x4 s[2];
#pragma unroll
        for (int ni = 0; ni < 2; ++ni) {
            s[ni] = (f32x4){-C, -C, -C, -C};
#pragma unroll
            for (int kd = 0; kd < 2; ++kd) {
                short8 kb = *(const short8*)(Kg + (size_t)(k0 + ni * 16 + l16) * NTD + kd * 32 + quad * 8);
                s[ni] = __builtin_amdgcn_mfma_f32_16x16x32_bf16(qa[kd], kb, s[ni], 0, 0, 0);
            }
        }

        // p = 2^s; per-lane l accumulation; P -> per-wave LDS (bf16)
        const bool full = (k0 + 32 <= klmin);   // wave-uniform
#pragma unroll
        for (int ni = 0; ni < 2; ++ni) {
#pragma unroll
            for (int rr = 0; rr < 4; ++rr) {
                float sv = s[ni][rr];
                if (!full) {
                    const int kpos = k0 + ni * 16 + l16;
                    sv = (kpos < kl[rr]) ? sv : -1e30f;
                }
                const float p = exp2f(sv);
                lp[rr] += p;
                const u32 u = __builtin_bit_cast(u32, p);
                Pw[swz(quad * 4 + rr, ni * 16 + l16)] = (u16)((u + 0x8000u) >> 16);
            }
        }

        // PV: A-frag from LDS, B-frags (V) direct from global Vt[d][t]
        const short8 pa = *(const short8*)&Pw[swz(l16, quad * 8)];
#pragma unroll
        for (int nt = 0; nt < 4; ++nt) {
            const short8 vb = *(const short8*)(Vtb + (size_t)(nt * 16 + l16) * NT + k0 + quad * 8);
            o[nt] = __builtin_amdgcn_mfma_f32_16x16x32_bf16(pa, vb, o[nt], 0, 0, 0);
        }
    }

    // epilogue: reduce l across the 16-lane row group, normalize, store
#pragma unroll
    for (int rr = 0; rr < 4; ++rr) {
        float l = lp[rr];
        l += __shfl_xor(l, 1);
        l += __shfl_xor(l, 2);
        l += __shfl_xor(l, 4);
        l += __shfl_xor(l, 8);
        const float inv = 1.0f / l;
        const size_t rowoff = (size_t)(b * NT + qbase + quad * 4 + rr) * ND + h * NDK;
#pragma unroll
        for (int nt = 0; nt < 4; ++nt)
            attn[rowoff + nt * 16 + l16] = f2bf(o[nt][rr] * inv);
    }
}

extern "C" void kernel_launch(void* const* d_in, const int* in_sizes, int n_in,
                              void* d_out, int out_size, void* d_ws, size_t ws_size,
                              hipStream_t stream) {
    const float* x    = (const float*)d_in[0];
    const int*   plen = (const int*)d_in[1];
    const float* wqkv = (const float*)d_in[2];
    const float* wo   = (const float*)d_in[3];
    float* out = (float*)d_out;

    char* ws = (char*)d_ws;
    u16* xb   = (u16*)(ws);                  // 16,777,216
    u16* wqb  = (u16*)(ws + 16777216);       //  6,291,456
    u16* wob  = (u16*)(ws + 23068672);       //  2,097,152
    u16* qkv  = (u16*)(ws + 25165824);       // 50,331,648
    u16* attn = (u16*)(ws + 75497472);       // 16,777,216
    u16* vtb  = (u16*)(ws + 92274688);       // 33,554,432  (total 125,829,120)

    cvt_bf16<<<4096, 256, 0, stream>>>(x, xb, NB * NT * ND);
    cvt_bf16<<<1536, 256, 0, stream>>>(wqkv, wqb, 3 * ND * ND);
    cvt_bf16<<<512, 256, 0, stream>>>(wo, wob, ND * ND);

    // QKV = x @ W_qkv^T  (M=8192, N=3072, K=1024)
    gemm_bt<u16><<<dim3(64, 24), 256, 0, stream>>>(xb, wqb, qkv, NB * NT, 3 * ND, ND);

    // V -> Vt[bh][d][t]
    transpose_v<<<dim3(64, 32), 256, 0, stream>>>(qkv, vtb);

    // attention (barrier-free flash)
    flash_prefix<<<dim3(64, 32), 256, 0, stream>>>(qkv, vtb, plen, attn);

    // out = attn @ W_o^T  (M=8192, N=1024, K=1024)
    gemm_bt<float><<<dim3(64, 8), 256, 0, stream>>>(attn, wob, out, NB * NT, ND, ND);
}

// Round 4
// 310.665 us; speedup vs baseline: 1.5832x; 1.5832x over previous
//
#include <hip/hip_runtime.h>
#include <stdint.h>

#define NB 4
#define NT 2048
#define ND 1024
#define NH 16
#define NDK 64
#define NTD 3072   // 3*ND

typedef __attribute__((ext_vector_type(8))) short short8;
typedef __attribute__((ext_vector_type(4))) float f32x4;
typedef unsigned short u16;
typedef unsigned int u32;

__device__ __forceinline__ u16 f2bf(float f) {
    u32 u = __builtin_bit_cast(u32, f);
    u += 0x7fffu + ((u >> 16) & 1u);   // RNE
    return (u16)(u >> 16);
}
__device__ __forceinline__ float bf2f(u16 s) {
    u32 u = ((u32)s) << 16;
    return __builtin_bit_cast(float, u);
}

__device__ __forceinline__ void gl_lds16(const u16* g, u16* l) {
    __builtin_amdgcn_global_load_lds(
        (const __attribute__((address_space(1))) u32*)g,
        (__attribute__((address_space(3))) u32*)l, 16, 0, 0);
}

// XOR-swizzled tile index (rows of 32 u16 / 64B, 4 atoms of 8 u16).
__device__ __forceinline__ int swz(int row, int col) {
    return row * 32 + ((((col >> 3) ^ (row >> 1) ^ (row >> 3)) & 3) << 3) + (col & 7);
}

// ---------------- fp32 -> bf16 (RNE) ----------------
__global__ __launch_bounds__(256) void cvt_bf16(const float* __restrict__ in,
                                                u16* __restrict__ out, int n) {
    int i = (blockIdx.x * 256 + threadIdx.x) * 8;
    if (i + 8 > n) return;
    float4 a = *(const float4*)(in + i);
    float4 b = *(const float4*)(in + i + 4);
    short8 r;
    r[0] = (short)f2bf(a.x); r[1] = (short)f2bf(a.y);
    r[2] = (short)f2bf(a.z); r[3] = (short)f2bf(a.w);
    r[4] = (short)f2bf(b.x); r[5] = (short)f2bf(b.y);
    r[6] = (short)f2bf(b.z); r[7] = (short)f2bf(b.w);
    *(short8*)(out + i) = r;
}

// ---------------- bf16 GEMM: C[M,N] = A[M,K] * Bm[N,K]^T ----------------
template <typename OutT>
__global__ __launch_bounds__(256) void gemm_bt(const u16* __restrict__ A,
                                               const u16* __restrict__ Bm,
                                               OutT* __restrict__ C,
                                               int M, int N, int K) {
    __shared__ __align__(16) u16 As[128 * 32];
    __shared__ __align__(16) u16 Bs[128 * 32];
    const int tid  = threadIdx.x;
    const int wave = tid >> 6, lane = tid & 63;
    const int quad = lane >> 4, l16 = lane & 15;
    const int wm = wave >> 1, wn = wave & 1;
    const int row0 = blockIdx.x * 128, col0 = blockIdx.y * 128;

    f32x4 acc[4][4];
#pragma unroll
    for (int i = 0; i < 4; ++i)
#pragma unroll
        for (int j = 0; j < 4; ++j) acc[i][j] = (f32x4){0.f, 0.f, 0.f, 0.f};

    const u16* Ag = A + (size_t)(row0 + (tid >> 2)) * K + ((tid & 3) * 8);
    const u16* Bg = Bm + (size_t)(col0 + (tid >> 2)) * K + ((tid & 3) * 8);
    const size_t stride64 = (size_t)64 * K;
    u16* As0 = As + wave * 512;
    u16* As1 = As + 2048 + wave * 512;
    u16* Bs0 = Bs + wave * 512;
    u16* Bs1 = Bs + 2048 + wave * 512;

    for (int k0 = 0; k0 < K; k0 += 32) {
        gl_lds16(Ag + k0, As0);
        gl_lds16(Ag + k0 + stride64, As1);
        gl_lds16(Bg + k0, Bs0);
        gl_lds16(Bg + k0 + stride64, Bs1);
        __syncthreads();
        short8 af[4], bfr[4];
#pragma unroll
        for (int mi = 0; mi < 4; ++mi)
            af[mi] = *(const short8*)&As[(wm * 64 + mi * 16 + l16) * 32 + quad * 8];
#pragma unroll
        for (int ni = 0; ni < 4; ++ni)
            bfr[ni] = *(const short8*)&Bs[(wn * 64 + ni * 16 + l16) * 32 + quad * 8];
#pragma unroll
        for (int mi = 0; mi < 4; ++mi)
#pragma unroll
            for (int ni = 0; ni < 4; ++ni)
                acc[mi][ni] = __builtin_amdgcn_mfma_f32_16x16x32_bf16(
                    af[mi], bfr[ni], acc[mi][ni], 0, 0, 0);
        __syncthreads();
    }

#pragma unroll
    for (int mi = 0; mi < 4; ++mi) {
#pragma unroll
        for (int ni = 0; ni < 4; ++ni) {
            const int r = row0 + wm * 64 + mi * 16 + quad * 4;
            const int c = col0 + wn * 64 + ni * 16 + l16;
#pragma unroll
            for (int rr = 0; rr < 4; ++rr) {
                float v = acc[mi][ni][rr];
                if constexpr (sizeof(OutT) == 2)
                    C[(size_t)(r + rr) * N + c] = (OutT)f2bf(v);
                else
                    C[(size_t)(r + rr) * N + c] = (OutT)v;
            }
        }
    }
}

// ---------------- V transpose: qkv V-section -> Vt[bh][d][t] ----------------
__global__ __launch_bounds__(256) void transpose_v(const u16* __restrict__ qkv,
                                                   u16* __restrict__ vt) {
    __shared__ __align__(16) u16 L[64 * 72];
    const int tid = threadIdx.x;
    const int bh = blockIdx.x, b = bh >> 4, h = bh & 15;
    const int t0 = blockIdx.y * 64;
    const u16* Vg = qkv + ((size_t)(b * NT + t0)) * NTD + 2 * ND + h * NDK;

    const int trow = tid >> 3, g = tid & 7;
#pragma unroll
    for (int rep = 0; rep < 2; ++rep) {
        const int t = trow + rep * 32;
        short8 v = *(const short8*)(Vg + (size_t)t * NTD + g * 8);
        *(short8*)&L[t * 72 + ((g ^ (t & 7)) << 3)] = v;
    }
    __syncthreads();
    const int d = tid & 63, w = tid >> 6;
    u16* O = vt + ((size_t)bh * 64 + d) * NT + t0;
#pragma unroll
    for (int rep = 0; rep < 2; ++rep) {
        const int c = w + rep * 4;
        short8 o;
#pragma unroll
        for (int j = 0; j < 8; ++j) {
            const int t = c * 8 + j;
            o[j] = L[t * 72 + ((((d >> 3) ^ (t & 7)) << 3)) + (d & 7)];
        }
        *(short8*)(O + c * 8) = o;
    }
}

// ---------------- flash prefix-LM attention (v4) ----------------
// grid (64 bh, 32 q-tiles). K and V tiles DMA'd to LDS (global_load_lds x16,
// swizzle baked into per-lane source addresses), double-buffered, ONE barrier
// per 32-key step with one-step-ahead prefetch. Constant-max exp2 softmax.
__global__ __launch_bounds__(256) void flash_prefix(const u16* __restrict__ qkv,
                                                    const u16* __restrict__ vt,
                                                    const int* __restrict__ plen,
                                                    u16* __restrict__ attn) {
    __shared__ __align__(16) u16 Vt2[2][2048];  // [d 64][t 32] swizzled rows of 32 u16
    __shared__ __align__(16) u16 Kt2[2][2048];  // [k 32][d 64] swizzled rows of 64 u16
    __shared__ __align__(16) u16 Pl[4 * 512];   // per-wave 16x32 swizzled

    const int tid  = threadIdx.x;
    const int wave = tid >> 6, lane = tid & 63;
    const int quad = lane >> 4, l16 = lane & 15;
    const int bh = blockIdx.x, b = bh >> 4, h = bh & 15;
    const int q0 = blockIdx.y * 64;

    int P;
    {
        bool is64 = (plen[1] == 0) && (plen[3] == 0);
        P = is64 ? plen[2 * b] : plen[b];
        P = P < 0 ? 0 : (P > NT ? NT : P);
    }

    const u16* Qg = qkv + (size_t)b * NT * NTD + h * NDK;
    const u16* Kg = Qg + ND;
    const u16* Vtb = vt + (size_t)bh * 64 * NT;   // [d][t]

    const int qbase = q0 + wave * 16;
    u16* Pw = Pl + wave * 512;

    const float C = 23.0831207f;           // 16*log2(e); cancels in o/l
    const float QSCALE = 0.18033688f;      // log2(e)/8

    // DMA lane->source mapping (swizzle baked into global address).
    // V tile: atom a=tid (16B), row=a>>2 (d), stored chunk tq = (a^ (row>>1)^(row>>3))&3
    const int va = tid;
    const int vrow = va >> 2;
    const int vtq = (va ^ (vrow >> 1) ^ (vrow >> 3)) & 3;
    const u16* vsrc = Vtb + (size_t)vrow * NT + vtq * 8;
    // K tile: atom a=tid, row=a>>3 (k), stored chunk c = (a ^ row)&7
    const int ka = tid;
    const int krow = ka >> 3;
    const int kc = (ka ^ krow) & 7;
    const u16* ksrc = Kg + (size_t)krow * NTD + kc * 8;
    const int ldsoff = wave * 512;  // u16; per-wave quarter (1KB)

    // Q fragments pre-scaled into exp2 domain
    short8 qa[2];
#pragma unroll
    for (int kd = 0; kd < 2; ++kd) {
        short8 tq = *(const short8*)(Qg + (size_t)(qbase + l16) * NTD + kd * 32 + quad * 8);
#pragma unroll
        for (int j = 0; j < 8; ++j)
            tq[j] = (short)f2bf(bf2f((u16)tq[j]) * QSCALE);
        qa[kd] = tq;
    }

    f32x4 o[4];
#pragma unroll
    for (int nt = 0; nt < 4; ++nt) o[nt] = (f32x4){0.f, 0.f, 0.f, 0.f};
    float lp[4] = {0.f, 0.f, 0.f, 0.f};

    int kl[4];
#pragma unroll
    for (int rr = 0; rr < 4; ++rr) {
        const int qrow = qbase + quad * 4 + rr;
        kl[rr] = (qrow < P) ? P : (qrow + 1);
    }
    const int klmin = (qbase < P) ? P : (qbase + 1);  // wave-uniform
    const int kmax = (q0 + 64 > P) ? (q0 + 64) : P;   // block-uniform

    // prefetch tile 0
    gl_lds16(vsrc, &Vt2[0][ldsoff]);
    gl_lds16(ksrc, &Kt2[0][ldsoff]);
    int buf = 0;

    for (int k0 = 0; k0 < kmax; k0 += 32) {
        __syncthreads();   // drains DMA for buf; all waves done reading buf^1
        if (k0 + 32 < kmax) {
            gl_lds16(vsrc + (k0 + 32), &Vt2[buf ^ 1][ldsoff]);
            gl_lds16(ksrc + (size_t)(k0 + 32) * NTD, &Kt2[buf ^ 1][ldsoff]);
        }
        const u16* Kb = Kt2[buf];
        const u16* Vb = Vt2[buf];

        // S = Q K^T + (-C): B-frags from swizzled K tile (rows of 64 u16)
        f32x4 s[2];
#pragma unroll
        for (int ni = 0; ni < 2; ++ni) {
            s[ni] = (f32x4){-C, -C, -C, -C};
#pragma unroll
            for (int kd = 0; kd < 2; ++kd) {
                const int r = ni * 16 + l16;
                const short8 kb = *(const short8*)&Kb[r * 64 + ((((kd * 4 + quad) ^ r) & 7) << 3)];
                s[ni] = __builtin_amdgcn_mfma_f32_16x16x32_bf16(qa[kd], kb, s[ni], 0, 0, 0);
            }
        }

        // p = 2^s; per-lane l accumulation; P -> per-wave LDS (bf16)
        const bool full = (k0 + 32 <= klmin);   // wave-uniform
#pragma unroll
        for (int ni = 0; ni < 2; ++ni) {
#pragma unroll
            for (int rr = 0; rr < 4; ++rr) {
                float sv = s[ni][rr];
                if (!full) {
                    const int kpos = k0 + ni * 16 + l16;
                    sv = (kpos < kl[rr]) ? sv : -1e30f;
                }
                const float p = exp2f(sv);
                lp[rr] += p;
                const u32 u = __builtin_bit_cast(u32, p);
                Pw[swz(quad * 4 + rr, ni * 16 + l16)] = (u16)((u + 0x8000u) >> 16);
            }
        }

        // PV: A-frag from per-wave P, B-frags from swizzled V tile
        const short8 pa = *(const short8*)&Pw[swz(l16, quad * 8)];
#pragma unroll
        for (int nt = 0; nt < 4; ++nt) {
            const short8 vb = *(const short8*)&Vb[swz(nt * 16 + l16, quad * 8)];
            o[nt] = __builtin_amdgcn_mfma_f32_16x16x32_bf16(pa, vb, o[nt], 0, 0, 0);
        }
        buf ^= 1;
    }

    // epilogue: reduce l across the 16-lane row group, normalize, store
#pragma unroll
    for (int rr = 0; rr < 4; ++rr) {
        float l = lp[rr];
        l += __shfl_xor(l, 1);
        l += __shfl_xor(l, 2);
        l += __shfl_xor(l, 4);
        l += __shfl_xor(l, 8);
        const float inv = 1.0f / l;
        const size_t rowoff = (size_t)(b * NT + qbase + quad * 4 + rr) * ND + h * NDK;
#pragma unroll
        for (int nt = 0; nt < 4; ++nt)
            attn[rowoff + nt * 16 + l16] = f2bf(o[nt][rr] * inv);
    }
}

extern "C" void kernel_launch(void* const* d_in, const int* in_sizes, int n_in,
                              void* d_out, int out_size, void* d_ws, size_t ws_size,
                              hipStream_t stream) {
    const float* x    = (const float*)d_in[0];
    const int*   plen = (const int*)d_in[1];
    const float* wqkv = (const float*)d_in[2];
    const float* wo   = (const float*)d_in[3];
    float* out = (float*)d_out;

    char* ws = (char*)d_ws;
    u16* xb   = (u16*)(ws);                  // 16,777,216
    u16* wqb  = (u16*)(ws + 16777216);       //  6,291,456
    u16* wob  = (u16*)(ws + 23068672);       //  2,097,152
    u16* qkv  = (u16*)(ws + 25165824);       // 50,331,648
    u16* attn = (u16*)(ws + 75497472);       // 16,777,216
    u16* vtb  = (u16*)(ws + 92274688);       // 33,554,432  (total 125,829,120)

    cvt_bf16<<<4096, 256, 0, stream>>>(x, xb, NB * NT * ND);
    cvt_bf16<<<1536, 256, 0, stream>>>(wqkv, wqb, 3 * ND * ND);
    cvt_bf16<<<512, 256, 0, stream>>>(wo, wob, ND * ND);

    // QKV = x @ W_qkv^T  (M=8192, N=3072, K=1024)
    gemm_bt<u16><<<dim3(64, 24), 256, 0, stream>>>(xb, wqb, qkv, NB * NT, 3 * ND, ND);

    // V -> Vt[bh][d][t]
    transpose_v<<<dim3(64, 32), 256, 0, stream>>>(qkv, vtb);

    // attention (double-buffered DMA flash)
    flash_prefix<<<dim3(64, 32), 256, 0, stream>>>(qkv, vtb, plen, attn);

    // out = attn @ W_o^T  (M=8192, N=1024, K=1024)
    gemm_bt<float><<<dim3(64, 8), 256, 0, stream>>>(attn, wob, out, NB * NT, ND, ND);
}

// Round 5
// 300.084 us; speedup vs baseline: 1.6390x; 1.0353x over previous
//
#include <hip/hip_runtime.h>
#include <stdint.h>

#define NB 4
#define NT 2048
#define ND 1024
#define NH 16
#define NDK 64
#define NTD 3072   // 3*ND

typedef __attribute__((ext_vector_type(8))) short short8;
typedef __attribute__((ext_vector_type(4))) float f32x4;
typedef unsigned short u16;
typedef unsigned int u32;

__device__ __forceinline__ u16 f2bf(float f) {
    u32 u = __builtin_bit_cast(u32, f);
    u += 0x7fffu + ((u >> 16) & 1u);   // RNE
    return (u16)(u >> 16);
}
__device__ __forceinline__ float bf2f(u16 s) {
    u32 u = ((u32)s) << 16;
    return __builtin_bit_cast(float, u);
}

__device__ __forceinline__ void gl_lds16(const u16* g, u16* l) {
    __builtin_amdgcn_global_load_lds(
        (const __attribute__((address_space(1))) u32*)g,
        (__attribute__((address_space(3))) u32*)l, 16, 0, 0);
}

// XOR-swizzled tile index (rows of 32 u16 / 64B, 4 atoms of 8 u16).
__device__ __forceinline__ int swz(int row, int col) {
    return row * 32 + ((((col >> 3) ^ (row >> 1) ^ (row >> 3)) & 3) << 3) + (col & 7);
}

// ---------------- fused fp32 -> bf16 (RNE) for x, W_qkv, W_o ----------------
__global__ __launch_bounds__(256) void cvt_all(const float* __restrict__ x,
                                               const float* __restrict__ wqkv,
                                               const float* __restrict__ wo,
                                               u16* __restrict__ xb,
                                               u16* __restrict__ wqb,
                                               u16* __restrict__ wob) {
    const int n0 = NB * NT * ND;       // 8388608
    const int n1 = 3 * ND * ND;        // 3145728
    int i = (blockIdx.x * 256 + threadIdx.x) * 8;
    const float* src;
    u16* dst;
    if (i < n0) {
        src = x + i; dst = xb + i;
    } else if (i < n0 + n1) {
        src = wqkv + (i - n0); dst = wqb + (i - n0);
    } else {
        src = wo + (i - n0 - n1); dst = wob + (i - n0 - n1);
    }
    float4 a = *(const float4*)(src);
    float4 b = *(const float4*)(src + 4);
    short8 r;
    r[0] = (short)f2bf(a.x); r[1] = (short)f2bf(a.y);
    r[2] = (short)f2bf(a.z); r[3] = (short)f2bf(a.w);
    r[4] = (short)f2bf(b.x); r[5] = (short)f2bf(b.y);
    r[6] = (short)f2bf(b.z); r[7] = (short)f2bf(b.w);
    *(short8*)(dst) = r;
}

// ---------------- bf16 GEMM: C[M,N] = A[M,K] * Bm[N,K]^T ----------------
template <typename OutT>
__global__ __launch_bounds__(256) void gemm_bt(const u16* __restrict__ A,
                                               const u16* __restrict__ Bm,
                                               OutT* __restrict__ C,
                                               int M, int N, int K) {
    __shared__ __align__(16) u16 As[128 * 32];
    __shared__ __align__(16) u16 Bs[128 * 32];
    const int tid  = threadIdx.x;
    const int wave = tid >> 6, lane = tid & 63;
    const int quad = lane >> 4, l16 = lane & 15;
    const int wm = wave >> 1, wn = wave & 1;
    const int row0 = blockIdx.x * 128, col0 = blockIdx.y * 128;

    f32x4 acc[4][4];
#pragma unroll
    for (int i = 0; i < 4; ++i)
#pragma unroll
        for (int j = 0; j < 4; ++j) acc[i][j] = (f32x4){0.f, 0.f, 0.f, 0.f};

    const u16* Ag = A + (size_t)(row0 + (tid >> 2)) * K + ((tid & 3) * 8);
    const u16* Bg = Bm + (size_t)(col0 + (tid >> 2)) * K + ((tid & 3) * 8);
    const size_t stride64 = (size_t)64 * K;
    u16* As0 = As + wave * 512;
    u16* As1 = As + 2048 + wave * 512;
    u16* Bs0 = Bs + wave * 512;
    u16* Bs1 = Bs + 2048 + wave * 512;

    for (int k0 = 0; k0 < K; k0 += 32) {
        gl_lds16(Ag + k0, As0);
        gl_lds16(Ag + k0 + stride64, As1);
        gl_lds16(Bg + k0, Bs0);
        gl_lds16(Bg + k0 + stride64, Bs1);
        __syncthreads();
        short8 af[4], bfr[4];
#pragma unroll
        for (int mi = 0; mi < 4; ++mi)
            af[mi] = *(const short8*)&As[(wm * 64 + mi * 16 + l16) * 32 + quad * 8];
#pragma unroll
        for (int ni = 0; ni < 4; ++ni)
            bfr[ni] = *(const short8*)&Bs[(wn * 64 + ni * 16 + l16) * 32 + quad * 8];
#pragma unroll
        for (int mi = 0; mi < 4; ++mi)
#pragma unroll
            for (int ni = 0; ni < 4; ++ni)
                acc[mi][ni] = __builtin_amdgcn_mfma_f32_16x16x32_bf16(
                    af[mi], bfr[ni], acc[mi][ni], 0, 0, 0);
        __syncthreads();
    }

#pragma unroll
    for (int mi = 0; mi < 4; ++mi) {
#pragma unroll
        for (int ni = 0; ni < 4; ++ni) {
            const int r = row0 + wm * 64 + mi * 16 + quad * 4;
            const int c = col0 + wn * 64 + ni * 16 + l16;
#pragma unroll
            for (int rr = 0; rr < 4; ++rr) {
                float v = acc[mi][ni][rr];
                if constexpr (sizeof(OutT) == 2)
                    C[(size_t)(r + rr) * N + c] = (OutT)f2bf(v);
                else
                    C[(size_t)(r + rr) * N + c] = (OutT)v;
            }
        }
    }
}

// ---------------- V transpose: qkv V-section -> Vt[bh][d][t] ----------------
__global__ __launch_bounds__(256) void transpose_v(const u16* __restrict__ qkv,
                                                   u16* __restrict__ vt) {
    __shared__ __align__(16) u16 L[64 * 72];
    const int tid = threadIdx.x;
    const int bh = blockIdx.x, b = bh >> 4, h = bh & 15;
    const int t0 = blockIdx.y * 64;
    const u16* Vg = qkv + ((size_t)(b * NT + t0)) * NTD + 2 * ND + h * NDK;

    const int trow = tid >> 3, g = tid & 7;
#pragma unroll
    for (int rep = 0; rep < 2; ++rep) {
        const int t = trow + rep * 32;
        short8 v = *(const short8*)(Vg + (size_t)t * NTD + g * 8);
        *(short8*)&L[t * 72 + ((g ^ (t & 7)) << 3)] = v;
    }
    __syncthreads();
    const int d = tid & 63, w = tid >> 6;
    u16* O = vt + ((size_t)bh * 64 + d) * NT + t0;
#pragma unroll
    for (int rep = 0; rep < 2; ++rep) {
        const int c = w + rep * 4;
        short8 o;
#pragma unroll
        for (int j = 0; j < 8; ++j) {
            const int t = c * 8 + j;
            o[j] = L[t * 72 + ((((d >> 3) ^ (t & 7)) << 3)) + (d & 7)];
        }
        *(short8*)(O + c * 8) = o;
    }
}

// ---------------- flash prefix-LM attention (v5) ----------------
// grid (64 bh, 32 q-tiles). K/V DMA'd to LDS (double-buffered, one barrier
// per 32-key step). exp2-domain softmax with NO constant (f32 can't overflow:
// |s|<=~25 in exp2 domain). Row-sum l via ones-MFMA (C-layout, matches o).
__global__ __launch_bounds__(256) void flash_prefix(const u16* __restrict__ qkv,
                                                    const u16* __restrict__ vt,
                                                    const int* __restrict__ plen,
                                                    u16* __restrict__ attn) {
    __shared__ __align__(16) u16 Vt2[2][2048];  // [d 64][t 32] swizzled rows of 32 u16
    __shared__ __align__(16) u16 Kt2[2][2048];  // [k 32][d 64] swizzled rows of 64 u16
    __shared__ __align__(16) u16 Pl[4 * 512];   // per-wave 16x32 swizzled

    const int tid  = threadIdx.x;
    const int wave = tid >> 6, lane = tid & 63;
    const int quad = lane >> 4, l16 = lane & 15;
    const int bh = blockIdx.x, b = bh >> 4, h = bh & 15;
    const int q0 = blockIdx.y * 64;

    int P;
    {
        bool is64 = (plen[1] == 0) && (plen[3] == 0);
        P = is64 ? plen[2 * b] : plen[b];
        P = P < 0 ? 0 : (P > NT ? NT : P);
    }

    const u16* Qg = qkv + (size_t)b * NT * NTD + h * NDK;
    const u16* Kg = Qg + ND;
    const u16* Vtb = vt + (size_t)bh * 64 * NT;   // [d][t]

    const int qbase = q0 + wave * 16;
    u16* Pw = Pl + wave * 512;

    const float QSCALE = 0.18033688f;      // log2(e)/8

    // DMA lane->source mapping (swizzle baked into global address).
    const int va = tid;
    const int vrow = va >> 2;
    const int vtq = (va ^ (vrow >> 1) ^ (vrow >> 3)) & 3;
    const u16* vsrc = Vtb + (size_t)vrow * NT + vtq * 8;
    const int ka = tid;
    const int krow = ka >> 3;
    const int kc = (ka ^ krow) & 7;
    const u16* ksrc = Kg + (size_t)krow * NTD + kc * 8;
    const int ldsoff = wave * 512;  // u16; per-wave quarter (1KB)

    // Q fragments pre-scaled into exp2 domain
    short8 qa[2];
#pragma unroll
    for (int kd = 0; kd < 2; ++kd) {
        short8 tq = *(const short8*)(Qg + (size_t)(qbase + l16) * NTD + kd * 32 + quad * 8);
#pragma unroll
        for (int j = 0; j < 8; ++j)
            tq[j] = (short)f2bf(bf2f((u16)tq[j]) * QSCALE);
        qa[kd] = tq;
    }

    // all-ones bf16 B-frag for the row-sum MFMA
    short8 ones;
#pragma unroll
    for (int j = 0; j < 8; ++j) ones[j] = (short)0x3F80;

    f32x4 o[4];
#pragma unroll
    for (int nt = 0; nt < 4; ++nt) o[nt] = (f32x4){0.f, 0.f, 0.f, 0.f};
    f32x4 lsum = (f32x4){0.f, 0.f, 0.f, 0.f};

    int kl[4];
#pragma unroll
    for (int rr = 0; rr < 4; ++rr) {
        const int qrow = qbase + quad * 4 + rr;
        kl[rr] = (qrow < P) ? P : (qrow + 1);
    }
    const int klmin = (qbase < P) ? P : (qbase + 1);  // wave-uniform
    const int kmax = (q0 + 64 > P) ? (q0 + 64) : P;   // block-uniform

    // prefetch tile 0
    gl_lds16(vsrc, &Vt2[0][ldsoff]);
    gl_lds16(ksrc, &Kt2[0][ldsoff]);
    int buf = 0;

    for (int k0 = 0; k0 < kmax; k0 += 32) {
        __syncthreads();   // drains DMA for buf; all waves done reading buf^1
        if (k0 + 32 < kmax) {
            gl_lds16(vsrc + (k0 + 32), &Vt2[buf ^ 1][ldsoff]);
            gl_lds16(ksrc + (size_t)(k0 + 32) * NTD, &Kt2[buf ^ 1][ldsoff]);
        }
        const u16* Kb = Kt2[buf];
        const u16* Vb = Vt2[buf];

        // S = Q K^T (exp2-domain, pre-scaled)
        f32x4 s[2];
#pragma unroll
        for (int ni = 0; ni < 2; ++ni) {
            s[ni] = (f32x4){0.f, 0.f, 0.f, 0.f};
#pragma unroll
            for (int kd = 0; kd < 2; ++kd) {
                const int r = ni * 16 + l16;
                const short8 kb = *(const short8*)&Kb[r * 64 + ((((kd * 4 + quad) ^ r) & 7) << 3)];
                s[ni] = __builtin_amdgcn_mfma_f32_16x16x32_bf16(qa[kd], kb, s[ni], 0, 0, 0);
            }
        }

        // p = 2^s -> bf16 P tile in per-wave LDS (hi16 stores)
        const bool full = (k0 + 32 <= klmin);   // wave-uniform
#pragma unroll
        for (int ni = 0; ni < 2; ++ni) {
#pragma unroll
            for (int rr = 0; rr < 4; ++rr) {
                float sv = s[ni][rr];
                if (!full) {
                    const int kpos = k0 + ni * 16 + l16;
                    sv = (kpos < kl[rr]) ? sv : -1e30f;
                }
                const float p = exp2f(sv);
                const u32 u = __builtin_bit_cast(u32, p) + 0x8000u;
                Pw[swz(quad * 4 + rr, ni * 16 + l16)] = (u16)(u >> 16);
            }
        }

        // PV + row-sum: A-frag from per-wave P
        const short8 pa = *(const short8*)&Pw[swz(l16, quad * 8)];
        lsum = __builtin_amdgcn_mfma_f32_16x16x32_bf16(pa, ones, lsum, 0, 0, 0);
#pragma unroll
        for (int nt = 0; nt < 4; ++nt) {
            const short8 vb = *(const short8*)&Vb[swz(nt * 16 + l16, quad * 8)];
            o[nt] = __builtin_amdgcn_mfma_f32_16x16x32_bf16(pa, vb, o[nt], 0, 0, 0);
        }
        buf ^= 1;
    }

    // epilogue: l is in the same C-layout as o -> no shuffles
#pragma unroll
    for (int rr = 0; rr < 4; ++rr) {
        const float inv = 1.0f / lsum[rr];
        const size_t rowoff = (size_t)(b * NT + qbase + quad * 4 + rr) * ND + h * NDK;
#pragma unroll
        for (int nt = 0; nt < 4; ++nt)
            attn[rowoff + nt * 16 + l16] = f2bf(o[nt][rr] * inv);
    }
}

extern "C" void kernel_launch(void* const* d_in, const int* in_sizes, int n_in,
                              void* d_out, int out_size, void* d_ws, size_t ws_size,
                              hipStream_t stream) {
    const float* x    = (const float*)d_in[0];
    const int*   plen = (const int*)d_in[1];
    const float* wqkv = (const float*)d_in[2];
    const float* wo   = (const float*)d_in[3];
    float* out = (float*)d_out;

    char* ws = (char*)d_ws;
    u16* xb   = (u16*)(ws);                  // 16,777,216
    u16* wqb  = (u16*)(ws + 16777216);       //  6,291,456
    u16* wob  = (u16*)(ws + 23068672);       //  2,097,152
    u16* qkv  = (u16*)(ws + 25165824);       // 50,331,648
    u16* attn = (u16*)(ws + 75497472);       // 16,777,216
    u16* vtb  = (u16*)(ws + 92274688);       // 33,554,432  (total 125,829,120)

    // fused conversions: x, W_qkv, W_o
    cvt_all<<<6144, 256, 0, stream>>>(x, wqkv, wo, xb, wqb, wob);

    // QKV = x @ W_qkv^T  (M=8192, N=3072, K=1024)
    gemm_bt<u16><<<dim3(64, 24), 256, 0, stream>>>(xb, wqb, qkv, NB * NT, 3 * ND, ND);

    // V -> Vt[bh][d][t]
    transpose_v<<<dim3(64, 32), 256, 0, stream>>>(qkv, vtb);

    // attention (double-buffered DMA flash)
    flash_prefix<<<dim3(64, 32), 256, 0, stream>>>(qkv, vtb, plen, attn);

    // out = attn @ W_o^T  (M=8192, N=1024, K=1024)
    gemm_bt<float><<<dim3(64, 8), 256, 0, stream>>>(attn, wob, out, NB * NT, ND, ND);
}